// Round 18
// baseline (292.823 us; speedup 1.0000x reference)
//
#include <hip/hip_runtime.h>
#include <hip/hip_bf16.h>
#include <math.h>

// All inputs and the output are FLOAT32 (reference dtype). The "bf16" in the
// harness label is a literal string, not a dtype indicator.
//
// History (compressed):
//  R1-R4 spill lessons; R5 per-lane weights -> vector L1 traffic; R6 s_load
//  serial chains on tiny grids; R7/R8 LDS parity weights (+pad); R9 COB split;
//  R10 XCD swizzle; R12 P=4; R13 head fusion regressed; R14 unroll-4 ->
//  280.9; R15 grid.sync ~140us/sync regressed hard; R16 k_prep merge -> 278.1.
//  L8 (wP, 44us) resisted 3 structural attacks; remaining cost = LDS issue +
//  staging barrier at ~31% occupancy.
//  Now: k_upconv_sp for L6-L8 -- px from blockIdx (grid parity split) + q=64
//  so each WAVE covers exactly one y row -> py wave-uniform -> weight address
//  fully uniform via readfirstlane -> s_load through constant cache. ZERO LDS,
//  zero staging, zero syncthreads. R6's s_load failure needed tiny grids; here
//  768-3072 blocks of TLP hide scalar-load latency.

#define HH 512
#define WWI 512
#define HWP (HH*WWI)

// Contiguous-chunk XCD swizzle (bijective when nwg % 8 == 0).
__device__ __forceinline__ int xcd_swz(int bx, int nbx) {
  if ((nbx & 7) == 0) {
    int c = nbx >> 3;
    return (bx & 7) * c + (bx >> 3);
  }
  return bx;
}

// ---------------- fold helper (per weight-matrix row n of [CO][Cin][3][3]) ----------------
__device__ __forceinline__ void fold_one(const float* __restrict__ w, float* __restrict__ f, int n)
{
  const float* ws = w + (size_t)n*9;
  float W[9];
  #pragma unroll
  for (int k = 0; k < 9; k++) W[k] = ws[k];

  float a[2][2][3];
  #pragma unroll
  for (int c = 0; c < 3; c++) {
    a[0][0][c] = W[c];          a[0][1][c] = W[3+c] + W[6+c];
    a[1][0][c] = W[c] + W[3+c]; a[1][1][c] = W[6+c];
  }
  float* fo = f + (size_t)n*16;
  #pragma unroll
  for (int py = 0; py < 2; py++)
    #pragma unroll
    for (int px = 0; px < 2; px++) {
      int p = py*2 + px;
      #pragma unroll
      for (int ky = 0; ky < 2; ky++) {
        float kx0 = (px == 0) ? a[py][ky][0] : (a[py][ky][0] + a[py][ky][1]);
        float kx1 = (px == 0) ? (a[py][ky][1] + a[py][ky][2]) : a[py][ky][2];
        fo[p*4 + ky*2 + 0] = kx0;
        fo[p*4 + ky*2 + 1] = kx1;
      }
    }
}

// ---------------- prep: weight folding (blocks 0-52) + layer0 (block 53) ----------------
__global__ void k_prep(const float* __restrict__ x, const float* __restrict__ w0,
                       const float* __restrict__ b0, float* __restrict__ outS,
                       const float* __restrict__ w1, const float* __restrict__ w2,
                       const float* __restrict__ w3, const float* __restrict__ w4,
                       const float* __restrict__ w5, const float* __restrict__ w6,
                       const float* __restrict__ w7, const float* __restrict__ w8,
                       float* __restrict__ f1, float* __restrict__ f2,
                       float* __restrict__ f3, float* __restrict__ f4,
                       float* __restrict__ f5, float* __restrict__ f6,
                       float* __restrict__ f7, float* __restrict__ f8)
{
  if (blockIdx.x < 53) {
    int idx = blockIdx.x*blockDim.x + threadIdx.x;
    const float* w; float* f; int n;
    if      (idx < 4224)  { w = w1; f = f1; n = idx; }          // L1: 64x66
    else if (idx < 8320)  { w = w2; f = f2; n = idx - 4224; }   // L2: 64x64
    else if (idx < 10368) { w = w3; f = f3; n = idx - 8320; }   // L3: 32x64
    else if (idx < 11392) { w = w4; f = f4; n = idx - 10368; }  // L4: 32x32
    else if (idx < 12416) { w = w5; f = f5; n = idx - 11392; }  // L5: 32x32
    else if (idx < 12928) { w = w6; f = f6; n = idx - 12416; }  // L6: 16x32
    else if (idx < 13184) { w = w7; f = f7; n = idx - 12928; }  // L7: 16x16
    else if (idx < 13440) { w = w8; f = f8; n = idx - 13184; }  // L8: 16x16
    else return;
    fold_one(w, f, n);
  } else {
    // layer0: 1x1 conv on 2x2 upsample + leakyrelu + coordconv
    for (int idx = threadIdx.x; idx < 3*66*4; idx += blockDim.x) {
      int pos = idx & 3;
      int c = (idx >> 2) % 66;
      int b = idx / (66*4);
      float v;
      if (c < 64) {
        float a = b0[c];
        #pragma unroll
        for (int ci = 0; ci < 3; ci++) a += w0[c*3+ci] * x[b*3+ci];
        v = (a >= 0.f) ? a : 0.01f*a;
      } else {
        int xx = pos & 1, yy = pos >> 1;
        v = (c == 64) ? 2.f*(float)xx : 2.f*(float)yy;
      }
      outS[idx] = v;
    }
  }
}

// ---------------- scalar parity upconv: one thread per OUTPUT SCALAR (L1-L5) ----------------
// blockIdx.y = co. LDS: that co's 4 parity weight sets, [p][ci], stride CIN+1
// float4s (parity blocks bank-offset 4 -> disjoint). CIN compile-time +
// unroll 4: independent iterations -> pipelined loads (R14-proven).
template<int CIN>
__global__ void k_upconv_s(const float* __restrict__ in, float* __restrict__ out,
                           const float* __restrict__ wfold, const float* __restrict__ bias,
                           int B, int CO, int Hin)
{
  extern __shared__ float4 wlds4[];            // [4][CIN+1]
  int nt = blockDim.x, tid = threadIdx.x;
  int co = blockIdx.y;
  const int stride = CIN + 1;
  const float4* wsrc = reinterpret_cast<const float4*>(wfold);
  for (int s = tid; s < CIN*4; s += nt) {
    int p = s & 3;
    int ci = s >> 2;
    wlds4[p*stride + ci] = wsrc[(size_t)(co*CIN + ci)*4 + p];
  }
  __syncthreads();

  int Hout = Hin * 2;
  int npix = B * Hout * Hout;
  int idx = blockIdx.x*nt + tid;
  if (idx >= npix) return;
  int x = idx % Hout;
  int y = (idx / Hout) % Hout;
  int b = idx / (Hout * Hout);

  int X = x >> 1, Y = y >> 1;
  int px = x & 1, py = y & 1;

  int r_lo = py ? Y : (Y > 0 ? Y-1 : 0);
  int r_hi = py ? (Y < Hin-1 ? Y+1 : Hin-1) : Y;
  int c_lo = px ? X : (X > 0 ? X-1 : 0);
  int c_hi = px ? (X < Hin-1 ? X+1 : Hin-1) : X;

  float acc = bias[co];

  const size_t plane = (size_t)Hin * Hin;
  const float* ibase = in + (size_t)b * CIN * plane;
  const float4* wb = wlds4 + (py*2 + px) * stride;

  #pragma unroll 4
  for (int ci = 0; ci < CIN; ci++) {
    const float* ip = ibase + (size_t)ci * plane;
    const float* rl = ip + (size_t)r_lo * Hin;
    const float* rh = ip + (size_t)r_hi * Hin;
    float4 w4 = wb[ci];
    acc += w4.x*rl[c_lo] + w4.y*rl[c_hi] + w4.z*rh[c_lo] + w4.w*rh[c_hi];
  }

  float v = (acc >= 0.f) ? acc : 0.01f*acc;
  out[((size_t)b*CO + co)*((size_t)Hout*Hout) + (size_t)y*Hout + x] = v;
}

// ---------------- scalar-pipe parity upconv (L6-L8): uniform weights, NO LDS ----------------
// blockIdx.y = co-slice*2 + px. q = Hout/(2*P) must equal 64 so each 64-lane
// wave covers exactly one y row -> py wave-uniform -> weight address uniform
// via readfirstlane -> s_load (constant cache), zero LDS/staging/barrier.
// X = x1 + k*q is px-independent; output column x = 2*X + px (stride-2 lanes;
// complementary-parity block fills the other columns, L2 merges lines).
template<int COB, int P>
__global__ void k_upconv_sp(const float* __restrict__ in, float* __restrict__ out,
                            const float* __restrict__ wfold, const float* __restrict__ bias,
                            int B, int Cin, int CO, int Hin)
{
  int px  = blockIdx.y & 1;
  int co0 = (blockIdx.y >> 1) * COB;
  int Hout = Hin * 2;
  const int q = 64;                         // = Hout/(2*P) by construction
  int total = B * Hout * q;
  int bx = xcd_swz(blockIdx.x, gridDim.x);
  int idx = bx*blockDim.x + threadIdx.x;
  if (idx >= total) return;                 // totals are exact multiples of 256
  int x1 = idx % q;
  int y  = (idx / q) % Hout;
  int b  = idx / (q * Hout);

  int py = y & 1;                           // wave-uniform: q=64 -> one y per wave
  int p4 = __builtin_amdgcn_readfirstlane(py*2 + px);
  const float4* wp = reinterpret_cast<const float4*>(wfold) + p4;  // + (co*Cin+ci)*4

  int Y = y >> 1;
  int r_lo = py ? Y : (Y > 0 ? Y-1 : 0);
  int r_hi = py ? (Y < Hin-1 ? Y+1 : Hin-1) : Y;

  int clo[P], chi[P];
  #pragma unroll
  for (int k = 0; k < P; k++) {
    int X = x1 + k*q;
    clo[k] = px ? X : (X > 0 ? X-1 : 0);
    chi[k] = px ? (X < Hin-1 ? X+1 : Hin-1) : X;
  }

  float acc[P][COB];
  #pragma unroll
  for (int j = 0; j < COB; j++) {
    float bv = bias[co0 + j];
    #pragma unroll
    for (int k = 0; k < P; k++) acc[k][j] = bv;
  }

  const size_t plane = (size_t)Hin * Hin;
  const float* ibase = in + (size_t)b * Cin * plane;

  for (int ci = 0; ci < Cin; ci++) {
    const float* ip = ibase + (size_t)ci * plane;
    const float* rl = ip + (size_t)r_lo * Hin;
    const float* rh = ip + (size_t)r_hi * Hin;
    float pl0[P], pl1[P], ph0[P], ph1[P];
    #pragma unroll
    for (int k = 0; k < P; k++) {
      pl0[k] = rl[clo[k]]; pl1[k] = rl[chi[k]];
      ph0[k] = rh[clo[k]]; ph1[k] = rh[chi[k]];
    }
    #pragma unroll
    for (int j = 0; j < COB; j++) {
      float4 w4 = wp[((size_t)(co0 + j)*Cin + ci)*4];   // uniform -> s_load
      #pragma unroll
      for (int k = 0; k < P; k++)
        acc[k][j] += w4.x*pl0[k] + w4.y*pl1[k] + w4.z*ph0[k] + w4.w*ph1[k];
    }
  }

  size_t oplane = (size_t)Hout * Hout;
  float* op = out + ((size_t)b * CO + co0) * oplane + (size_t)y*Hout + 2*x1 + px;
  #pragma unroll
  for (int j = 0; j < COB; j++) {
    #pragma unroll
    for (int k = 0; k < P; k++) {
      float v = acc[k][j];
      v = (v >= 0.f) ? v : 0.01f*v;
      op[2*k*q] = v;
    }
    op += oplane;              // incremental: no per-co 64-bit mul
  }
}

// ---------------- final: reflect-pad + 3x3 conv (16 -> 6) + tanh, paired x ----------------
__global__ void k_final2(const float* __restrict__ in, float* __restrict__ out,
                         const float* __restrict__ w, const float* __restrict__ bias)
{
  int total = 3 * HH * (WWI/2);
  int bx = xcd_swz(blockIdx.x, gridDim.x);
  int idx = bx*blockDim.x + threadIdx.x;
  if (idx >= total) return;
  int xh = idx % (WWI/2);
  int y  = (idx / (WWI/2)) % HH;
  int b  = idx / (HH * (WWI/2));
  int x0 = 2*xh;

  int ry[3];
  #pragma unroll
  for (int d = 0; d < 3; d++) {
    int t = y - 1 + d;
    t = (t < 0) ? -t : t;
    ry[d] = (t >= HH) ? (2*(HH-1) - t) : t;
  }
  int cx[4];
  cx[0] = (x0 == 0) ? 1 : x0-1;
  cx[1] = x0;
  cx[2] = x0+1;
  cx[3] = (x0+2 >= WWI) ? (2*(WWI-1) - (x0+2)) : x0+2;

  float acc0[6], acc1[6];
  #pragma unroll
  for (int co = 0; co < 6; co++) { float bv = bias[co]; acc0[co] = bv; acc1[co] = bv; }

  for (int ci = 0; ci < 16; ci++) {
    const float* ib = in + ((size_t)(b*16) + ci) * HWP;
    float p[3][4];
    #pragma unroll
    for (int dy = 0; dy < 3; dy++) {
      const float* r = ib + (size_t)ry[dy]*WWI;
      #pragma unroll
      for (int dx = 0; dx < 4; dx++) p[dy][dx] = r[cx[dx]];
    }
    const float* wc = w + ci*9;
    #pragma unroll
    for (int co = 0; co < 6; co++) {
      const float* wcc = wc + co*16*9;
      #pragma unroll
      for (int dy = 0; dy < 3; dy++) {
        #pragma unroll
        for (int dx = 0; dx < 3; dx++) {
          float wv = wcc[dy*3+dx];
          acc0[co] += wv * p[dy][dx];
          acc1[co] += wv * p[dy][dx+1];
        }
      }
    }
  }

  size_t pix = (size_t)y*WWI + x0;
  #pragma unroll
  for (int co = 0; co < 6; co++) {
    float2 v = make_float2(tanhf(acc0[co]), tanhf(acc1[co]));
    *reinterpret_cast<float2*>(out + ((size_t)(b*6) + co)*HWP + pix) = v;
  }
}

// ---------------- blending: fused grid-sample + weighting (all fp32) ----------------
__global__ void k_blend(const float* __restrict__ xin, const float* __restrict__ neighbors,
                        const int* __restrict__ aidx, const float* __restrict__ albedos,
                        const float* __restrict__ flows, float* __restrict__ out)
{
  int idx = blockIdx.x*blockDim.x + threadIdx.x;
  if (idx >= HWP) return;
  int xo = idx & (WWI-1);
  int yo = idx >> 9;

  float xv[9];
  #pragma unroll
  for (int i = 0; i < 9; i++) xv[i] = xin[i];

  float f0[6];
  #pragma unroll
  for (int c = 0; c < 6; c++) f0[c] = flows[(size_t)c*HWP + idx];

  const float* alb = albedos + (size_t)aidx[0]*3*HWP;
  float albp[3];
  #pragma unroll
  for (int ch = 0; ch < 3; ch++) albp[ch] = alb[(size_t)ch*HWP + idx];

  float num0 = 0.f, num1 = 0.f, num2 = 0.f;
  float wsum = 0.f;

  #pragma unroll
  for (int n = 0; n < 2; n++) {
    float dl = xv[0] - xv[(n+1)*3 + 0];
    float dv = xv[1] - xv[(n+1)*3 + 1];
    float dt = xv[2] - xv[(n+1)*3 + 2];
    bool fl = fabsf(dl) > 0.f;

    float ofx = dl*f0[0] + dv*f0[2] + dt*f0[4];
    float ofy = dl*f0[1] + dv*f0[3] + dt*f0[5];

    float gx = ((-1.f + (2.f/511.f)*(float)xo) + ofx + 1.f)*256.f - 0.5f;
    float gy = ((-1.f + (2.f/511.f)*(float)yo) + ofy + 1.f)*256.f - 0.5f;
    gx = fminf(fmaxf(gx, 0.f), 511.f);
    gy = fminf(fmaxf(gy, 0.f), 511.f);

    float x0f = floorf(gx), y0f = floorf(gy);
    float wx = gx - x0f, wy = gy - y0f;
    int x0i = (int)x0f, y0i = (int)y0f;
    int x1i = min(x0i + 1, WWI-1), y1i = min(y0i + 1, HH-1);

    float cw[4] = {(1.f-wx)*(1.f-wy), wx*(1.f-wy), (1.f-wx)*wy, wx*wy};
    int   cp[4] = {y0i*WWI + x0i, y0i*WWI + x1i, y1i*WWI + x0i, y1i*WWI + x1i};

    const float* nb = neighbors + (size_t)n*3*HWP;
    const float* Fn = flows + (size_t)(n+1)*6*HWP;

    float s0=0.f,s1=0.f,s2=0.f;
    float l0=0.f,l1=0.f,v0=0.f,v1=0.f,t0=0.f,t1=0.f;
    #pragma unroll
    for (int c = 0; c < 4; c++) {
      int p = cp[c];
      float ww = cw[c];
      float n0 = nb[p];
      float n1 = nb[HWP + p];
      float n2 = nb[2*HWP + p];
      if (fl) {
        n0 /= alb[p];
        n1 /= alb[HWP + p];
        n2 /= alb[2*HWP + p];
      }
      s0 += ww*n0; s1 += ww*n1; s2 += ww*n2;
      l0 += ww*Fn[p];             l1 += ww*Fn[HWP + p];
      v0 += ww*Fn[2*HWP + p];     v1 += ww*Fn[3*HWP + p];
      t0 += ww*Fn[4*HWP + p];     t1 += ww*Fn[5*HWP + p];
    }

    float wi0 = fl ? s0*albp[0] : s0;
    float wi1 = fl ? s1*albp[1] : s1;
    float wi2 = fl ? s2*albp[2] : s2;

    float obx = dl*l0 + dv*v0 + dt*t0;
    float oby = dl*l1 + dv*v1 + dt*t1;
    float dist = fabsf(ofx - obx) + fabsf(ofy - oby);
    float wgt = expf(-51.2f * dist);

    wsum += wgt;
    num0 += wgt*wi0; num1 += wgt*wi1; num2 += wgt*wi2;
  }

  float inv = 1.f / (wsum + 1e-5f);
  out[idx]         = num0*inv;
  out[HWP + idx]   = num1*inv;
  out[2*HWP + idx] = num2*inv;
}

// ---------------- launch ----------------
extern "C" void kernel_launch(void* const* d_in, const int* in_sizes, int n_in,
                              void* d_out, int out_size, void* d_ws, size_t ws_size,
                              hipStream_t stream) {
  const float* x         = (const float*)d_in[0];
  const float* neighbors = (const float*)d_in[1];
  const int*   aidx      = (const int*)d_in[2];
  const float* wts[10];
  const float* bis[10];
  for (int i = 0; i < 9; i++) { wts[i] = (const float*)d_in[3+2*i]; bis[i] = (const float*)d_in[4+2*i]; }
  wts[9] = (const float*)d_in[21];   // wf
  bis[9] = (const float*)d_in[22];   // bf
  const float* albedos = (const float*)d_in[23];

  float* wk   = (float*)d_ws;
  float* bufS = wk;                   // 792 floats (layer0 out)
  float* bufA = wk + 800;             // up to 4,718,592 floats
  float* bufB = bufA + 4718592;       // up to 12,582,912 floats
  size_t need = (size_t)(800 + 4718592 + 12582912) * 4;
  if (ws_size < need) return;

  // Folded weights in bufA slack [3,200,000, 3,415,040): above L7's peak bufA
  // use (3,145,728 floats); overwritten only by k_final2 (4,718,592) AFTER L8
  // consumed them. No workspace growth.
  float* wf1 = bufA + 3200000;            // 64*66*16 = 67584
  float* wf2 = wf1 + 67584;               // 64*64*16 = 65536
  float* wf3 = wf2 + 65536;               // 32*64*16 = 32768
  float* wf4 = wf3 + 32768;               // 32*32*16 = 16384
  float* wf5 = wf4 + 16384;               // 32*32*16 = 16384
  float* wf6 = wf5 + 16384;               // 16*32*16 = 8192
  float* wf7 = wf6 + 8192;                // 16*16*16 = 4096
  float* wf8 = wf7 + 4096;                // 16*16*16 = 4096

  // prep: fold (blocks 0-52) + layer0 (block 53) -- one dispatch.
  k_prep<<<54, 256, 0, stream>>>(x, wts[0], bis[0], bufS,
                                 wts[1], wts[2], wts[3], wts[4], wts[5], wts[6], wts[7], wts[8],
                                 wf1, wf2, wf3, wf4, wf5, wf6, wf7, wf8);

  auto blocks = [](int total){ return (total + 255) / 256; };

  // L1-L5: scalar parity upconv, grid (npix/256, CO). LDS = 4*(CIN+1)*16 B.
  {
    dim3 g1(blocks(3*4*4), 64), g2(blocks(3*8*8), 64);
    dim3 g3(blocks(3*16*16), 32), g4(blocks(3*32*32), 32), g5(blocks(3*64*64), 32);
    k_upconv_s<66><<<g1, 256, (size_t)4*(66+1)*16, stream>>>(bufS, bufA, wf1, bis[1], 3, 64, 2);
    k_upconv_s<64><<<g2, 256, (size_t)4*(64+1)*16, stream>>>(bufA, bufB, wf2, bis[2], 3, 64, 4);
    k_upconv_s<64><<<g3, 256, (size_t)4*(64+1)*16, stream>>>(bufB, bufA, wf3, bis[3], 3, 32, 8);
    k_upconv_s<32><<<g4, 256, (size_t)4*(32+1)*16, stream>>>(bufA, bufB, wf4, bis[4], 3, 32, 16);
    k_upconv_s<32><<<g5, 256, (size_t)4*(32+1)*16, stream>>>(bufB, bufA, wf5, bis[5], 3, 32, 32);
  }

  // L6-L8: scalar-pipe uniform-weight upconv, blockIdx.y = co-slice*2 + px.
  // q=64 in all cases (Hout/(2P)): L6 P=1, L7 P=2, L8 P=4.
  {
    dim3 g6(blocks(3*128*64), 8);    // 96 x (4 co-slices * 2 px)
    dim3 g7(blocks(3*256*64), 8);    // 192 x 8
    dim3 g8(blocks(3*512*64), 8);    // 384 x 8
    k_upconv_sp<4,1><<<g6, 256, 0, stream>>>(bufA, bufB, wf6, bis[6], 3, 32, 16, 64);
    k_upconv_sp<4,2><<<g7, 256, 0, stream>>>(bufB, bufA, wf7, bis[7], 3, 16, 16, 128);
    k_upconv_sp<4,4><<<g8, 256, 0, stream>>>(bufA, bufB, wf8, bis[8], 3, 16, 16, 256);
  }

  // final: paired-x conv + tanh (+XCD swizzle).
  k_final2<<<blocks(3*HH*(WWI/2)), 256, 0, stream>>>(bufB, bufA, wts[9], bis[9]);
  k_blend<<<blocks(HWP), 256, 0, stream>>>(x, neighbors, aidx, albedos, bufA, (float*)d_out);
}

// Round 19
// 276.531 us; speedup vs baseline: 1.0589x; 1.0589x over previous
//
#include <hip/hip_runtime.h>
#include <hip/hip_bf16.h>
#include <math.h>

// All inputs and the output are FLOAT32 (reference dtype). The "bf16" in the
// harness label is a literal string, not a dtype indicator.
//
// History (compressed):
//  R1-R4 spill lessons (excess WRITE_SIZE is the tell); R5 per-lane weights ->
//  vector L1 traffic; R6 s_load serial chains on tiny grids; R7/R8 LDS parity
//  weights (+1-float4 pad = disjoint banks); R9 COB split; R10 XCD swizzle;
//  R12 P=4; R13 head fusion regressed; R14 unroll-4 -> 280.9; R15 grid.sync
//  ~140us/sync regressed hard; R16 k_prep merge -> 278.1 (BEST); R18
//  k_upconv_sp regressed L8 44->50.6us: stride-2 stores -> half-line writes ->
//  WRITE 70.8 vs 49.2MB (scalar-pipe weights not worth non-contiguous stores).
//  Now: byte-exact revert to R16. L8=44us has beaten 5 alternative structures;
//  pipes balanced (VALU 62%, LDS, global-lat) -> no single fixable resource.

#define HH 512
#define WWI 512
#define HWP (HH*WWI)

// Contiguous-chunk XCD swizzle (bijective when nwg % 8 == 0).
__device__ __forceinline__ int xcd_swz(int bx, int nbx) {
  if ((nbx & 7) == 0) {
    int c = nbx >> 3;
    return (bx & 7) * c + (bx >> 3);
  }
  return bx;
}

// ---------------- fold helper (per weight-matrix row n of [CO][Cin][3][3]) ----------------
__device__ __forceinline__ void fold_one(const float* __restrict__ w, float* __restrict__ f, int n)
{
  const float* ws = w + (size_t)n*9;
  float W[9];
  #pragma unroll
  for (int k = 0; k < 9; k++) W[k] = ws[k];

  float a[2][2][3];
  #pragma unroll
  for (int c = 0; c < 3; c++) {
    a[0][0][c] = W[c];          a[0][1][c] = W[3+c] + W[6+c];
    a[1][0][c] = W[c] + W[3+c]; a[1][1][c] = W[6+c];
  }
  float* fo = f + (size_t)n*16;
  #pragma unroll
  for (int py = 0; py < 2; py++)
    #pragma unroll
    for (int px = 0; px < 2; px++) {
      int p = py*2 + px;
      #pragma unroll
      for (int ky = 0; ky < 2; ky++) {
        float kx0 = (px == 0) ? a[py][ky][0] : (a[py][ky][0] + a[py][ky][1]);
        float kx1 = (px == 0) ? (a[py][ky][1] + a[py][ky][2]) : a[py][ky][2];
        fo[p*4 + ky*2 + 0] = kx0;
        fo[p*4 + ky*2 + 1] = kx1;
      }
    }
}

// ---------------- prep: weight folding (blocks 0-52) + layer0 (block 53) ----------------
__global__ void k_prep(const float* __restrict__ x, const float* __restrict__ w0,
                       const float* __restrict__ b0, float* __restrict__ outS,
                       const float* __restrict__ w1, const float* __restrict__ w2,
                       const float* __restrict__ w3, const float* __restrict__ w4,
                       const float* __restrict__ w5, const float* __restrict__ w6,
                       const float* __restrict__ w7, const float* __restrict__ w8,
                       float* __restrict__ f1, float* __restrict__ f2,
                       float* __restrict__ f3, float* __restrict__ f4,
                       float* __restrict__ f5, float* __restrict__ f6,
                       float* __restrict__ f7, float* __restrict__ f8)
{
  if (blockIdx.x < 53) {
    int idx = blockIdx.x*blockDim.x + threadIdx.x;
    const float* w; float* f; int n;
    if      (idx < 4224)  { w = w1; f = f1; n = idx; }          // L1: 64x66
    else if (idx < 8320)  { w = w2; f = f2; n = idx - 4224; }   // L2: 64x64
    else if (idx < 10368) { w = w3; f = f3; n = idx - 8320; }   // L3: 32x64
    else if (idx < 11392) { w = w4; f = f4; n = idx - 10368; }  // L4: 32x32
    else if (idx < 12416) { w = w5; f = f5; n = idx - 11392; }  // L5: 32x32
    else if (idx < 12928) { w = w6; f = f6; n = idx - 12416; }  // L6: 16x32
    else if (idx < 13184) { w = w7; f = f7; n = idx - 12928; }  // L7: 16x16
    else if (idx < 13440) { w = w8; f = f8; n = idx - 13184; }  // L8: 16x16
    else return;
    fold_one(w, f, n);
  } else {
    // layer0: 1x1 conv on 2x2 upsample + leakyrelu + coordconv
    for (int idx = threadIdx.x; idx < 3*66*4; idx += blockDim.x) {
      int pos = idx & 3;
      int c = (idx >> 2) % 66;
      int b = idx / (66*4);
      float v;
      if (c < 64) {
        float a = b0[c];
        #pragma unroll
        for (int ci = 0; ci < 3; ci++) a += w0[c*3+ci] * x[b*3+ci];
        v = (a >= 0.f) ? a : 0.01f*a;
      } else {
        int xx = pos & 1, yy = pos >> 1;
        v = (c == 64) ? 2.f*(float)xx : 2.f*(float)yy;
      }
      outS[idx] = v;
    }
  }
}

// ---------------- scalar parity upconv: one thread per OUTPUT SCALAR (L1-L5) ----------------
// blockIdx.y = co. LDS: that co's 4 parity weight sets, [p][ci], stride CIN+1
// float4s (parity blocks bank-offset 4 -> disjoint). CIN compile-time +
// unroll 4: independent iterations -> pipelined loads (R14-proven).
template<int CIN>
__global__ void k_upconv_s(const float* __restrict__ in, float* __restrict__ out,
                           const float* __restrict__ wfold, const float* __restrict__ bias,
                           int B, int CO, int Hin)
{
  extern __shared__ float4 wlds4[];            // [4][CIN+1]
  int nt = blockDim.x, tid = threadIdx.x;
  int co = blockIdx.y;
  const int stride = CIN + 1;
  const float4* wsrc = reinterpret_cast<const float4*>(wfold);
  for (int s = tid; s < CIN*4; s += nt) {
    int p = s & 3;
    int ci = s >> 2;
    wlds4[p*stride + ci] = wsrc[(size_t)(co*CIN + ci)*4 + p];
  }
  __syncthreads();

  int Hout = Hin * 2;
  int npix = B * Hout * Hout;
  int idx = blockIdx.x*nt + tid;
  if (idx >= npix) return;
  int x = idx % Hout;
  int y = (idx / Hout) % Hout;
  int b = idx / (Hout * Hout);

  int X = x >> 1, Y = y >> 1;
  int px = x & 1, py = y & 1;

  int r_lo = py ? Y : (Y > 0 ? Y-1 : 0);
  int r_hi = py ? (Y < Hin-1 ? Y+1 : Hin-1) : Y;
  int c_lo = px ? X : (X > 0 ? X-1 : 0);
  int c_hi = px ? (X < Hin-1 ? X+1 : Hin-1) : X;

  float acc = bias[co];

  const size_t plane = (size_t)Hin * Hin;
  const float* ibase = in + (size_t)b * CIN * plane;
  const float4* wb = wlds4 + (py*2 + px) * stride;

  #pragma unroll 4
  for (int ci = 0; ci < CIN; ci++) {
    const float* ip = ibase + (size_t)ci * plane;
    const float* rl = ip + (size_t)r_lo * Hin;
    const float* rh = ip + (size_t)r_hi * Hin;
    float4 w4 = wb[ci];
    acc += w4.x*rl[c_lo] + w4.y*rl[c_hi] + w4.z*rh[c_lo] + w4.w*rh[c_hi];
  }

  float v = (acc >= 0.f) ? acc : 0.01f*acc;
  out[((size_t)b*CO + co)*((size_t)Hout*Hout) + (size_t)y*Hout + x] = v;
}

// ---------------- P-position + co-split LDS-weight upconv (L6-L8, R12-proven) ----------------
// One thread = P x-positions (x1 + k*Hout/P, same px parity since Hout/P even)
// x COB channels; blockIdx.y = co-slice. One ds_read_b128 feeds 4*P FMAs.
template<int COB, int P>
__global__ void k_upconv_wP(const float* __restrict__ in, float* __restrict__ out,
                            const float* __restrict__ wfold, const float* __restrict__ bias,
                            int B, int Cin, int CO, int Hin)
{
  extern __shared__ float4 wlds4[];           // [4][Cin*COB + 1]
  int nt = blockDim.x, tid = threadIdx.x;
  int co0 = blockIdx.y * COB;
  int stride = Cin * COB + 1;                 // +1 float4 pad -> parity blocks on disjoint banks
  int nw = Cin * COB * 4;
  const float4* wsrc = reinterpret_cast<const float4*>(wfold);
  for (int s = tid; s < nw; s += nt) {
    int p = s & 3;
    int r = s >> 2;            // col*Cin + ci  (col = local co)
    int ci = r % Cin;
    int col = r / Cin;
    wlds4[p*stride + ci*COB + col] = wsrc[(size_t)((co0 + col)*Cin + ci)*4 + p];
  }
  __syncthreads();

  int Hout = Hin * 2;
  int q = Hout / P;
  int total = B * Hout * q;
  int bx = xcd_swz(blockIdx.x, gridDim.x);
  int idx = bx*nt + tid;
  if (idx >= total) return;
  int x1 = idx % q;
  int y  = (idx / q) % Hout;
  int b  = idx / (q * Hout);

  int px = x1 & 1, py = y & 1;
  int Y = y >> 1;
  int r_lo = py ? Y : (Y > 0 ? Y-1 : 0);
  int r_hi = py ? (Y < Hin-1 ? Y+1 : Hin-1) : Y;

  int clo[P], chi[P];
  #pragma unroll
  for (int k = 0; k < P; k++) {
    int X = (x1 + k*q) >> 1;
    clo[k] = px ? X : (X > 0 ? X-1 : 0);
    chi[k] = px ? (X < Hin-1 ? X+1 : Hin-1) : X;
  }

  float acc[P][COB];
  #pragma unroll
  for (int j = 0; j < COB; j++) {
    float bv = bias[co0 + j];
    #pragma unroll
    for (int k = 0; k < P; k++) acc[k][j] = bv;
  }

  const size_t plane = (size_t)Hin * Hin;
  const float* ibase = in + (size_t)b * Cin * plane;
  const float4* wb = wlds4 + (py*2 + px) * stride;

  for (int ci = 0; ci < Cin; ci++) {
    const float* ip = ibase + (size_t)ci * plane;
    const float* rl = ip + (size_t)r_lo * Hin;
    const float* rh = ip + (size_t)r_hi * Hin;
    float pl0[P], pl1[P], ph0[P], ph1[P];
    #pragma unroll
    for (int k = 0; k < P; k++) {
      pl0[k] = rl[clo[k]]; pl1[k] = rl[chi[k]];
      ph0[k] = rh[clo[k]]; ph1[k] = rh[chi[k]];
    }
    const float4* wc = wb + ci * COB;
    #pragma unroll
    for (int j = 0; j < COB; j++) {
      float4 w4 = wc[j];                      // 1 ds_read_b128 -> 4*P FMAs
      #pragma unroll
      for (int k = 0; k < P; k++)
        acc[k][j] += w4.x*pl0[k] + w4.y*pl1[k] + w4.z*ph0[k] + w4.w*ph1[k];
    }
  }

  size_t oplane = (size_t)Hout * Hout;
  float* op = out + ((size_t)b * CO + co0) * oplane + (size_t)y*Hout + x1;
  #pragma unroll
  for (int j = 0; j < COB; j++) {
    #pragma unroll
    for (int k = 0; k < P; k++) {
      float v = acc[k][j];
      v = (v >= 0.f) ? v : 0.01f*v;
      op[k*q] = v;
    }
    op += oplane;              // incremental: no per-co 64-bit mul
  }
}

// ---------------- final: reflect-pad + 3x3 conv (16 -> 6) + tanh, paired x ----------------
__global__ void k_final2(const float* __restrict__ in, float* __restrict__ out,
                         const float* __restrict__ w, const float* __restrict__ bias)
{
  int total = 3 * HH * (WWI/2);
  int bx = xcd_swz(blockIdx.x, gridDim.x);
  int idx = bx*blockDim.x + threadIdx.x;
  if (idx >= total) return;
  int xh = idx % (WWI/2);
  int y  = (idx / (WWI/2)) % HH;
  int b  = idx / (HH * (WWI/2));
  int x0 = 2*xh;

  int ry[3];
  #pragma unroll
  for (int d = 0; d < 3; d++) {
    int t = y - 1 + d;
    t = (t < 0) ? -t : t;
    ry[d] = (t >= HH) ? (2*(HH-1) - t) : t;
  }
  int cx[4];
  cx[0] = (x0 == 0) ? 1 : x0-1;
  cx[1] = x0;
  cx[2] = x0+1;
  cx[3] = (x0+2 >= WWI) ? (2*(WWI-1) - (x0+2)) : x0+2;

  float acc0[6], acc1[6];
  #pragma unroll
  for (int co = 0; co < 6; co++) { float bv = bias[co]; acc0[co] = bv; acc1[co] = bv; }

  for (int ci = 0; ci < 16; ci++) {
    const float* ib = in + ((size_t)(b*16) + ci) * HWP;
    float p[3][4];
    #pragma unroll
    for (int dy = 0; dy < 3; dy++) {
      const float* r = ib + (size_t)ry[dy]*WWI;
      #pragma unroll
      for (int dx = 0; dx < 4; dx++) p[dy][dx] = r[cx[dx]];
    }
    const float* wc = w + ci*9;
    #pragma unroll
    for (int co = 0; co < 6; co++) {
      const float* wcc = wc + co*16*9;
      #pragma unroll
      for (int dy = 0; dy < 3; dy++) {
        #pragma unroll
        for (int dx = 0; dx < 3; dx++) {
          float wv = wcc[dy*3+dx];
          acc0[co] += wv * p[dy][dx];
          acc1[co] += wv * p[dy][dx+1];
        }
      }
    }
  }

  size_t pix = (size_t)y*WWI + x0;
  #pragma unroll
  for (int co = 0; co < 6; co++) {
    float2 v = make_float2(tanhf(acc0[co]), tanhf(acc1[co]));
    *reinterpret_cast<float2*>(out + ((size_t)(b*6) + co)*HWP + pix) = v;
  }
}

// ---------------- blending: fused grid-sample + weighting (all fp32) ----------------
__global__ void k_blend(const float* __restrict__ xin, const float* __restrict__ neighbors,
                        const int* __restrict__ aidx, const float* __restrict__ albedos,
                        const float* __restrict__ flows, float* __restrict__ out)
{
  int idx = blockIdx.x*blockDim.x + threadIdx.x;
  if (idx >= HWP) return;
  int xo = idx & (WWI-1);
  int yo = idx >> 9;

  float xv[9];
  #pragma unroll
  for (int i = 0; i < 9; i++) xv[i] = xin[i];

  float f0[6];
  #pragma unroll
  for (int c = 0; c < 6; c++) f0[c] = flows[(size_t)c*HWP + idx];

  const float* alb = albedos + (size_t)aidx[0]*3*HWP;
  float albp[3];
  #pragma unroll
  for (int ch = 0; ch < 3; ch++) albp[ch] = alb[(size_t)ch*HWP + idx];

  float num0 = 0.f, num1 = 0.f, num2 = 0.f;
  float wsum = 0.f;

  #pragma unroll
  for (int n = 0; n < 2; n++) {
    float dl = xv[0] - xv[(n+1)*3 + 0];
    float dv = xv[1] - xv[(n+1)*3 + 1];
    float dt = xv[2] - xv[(n+1)*3 + 2];
    bool fl = fabsf(dl) > 0.f;

    float ofx = dl*f0[0] + dv*f0[2] + dt*f0[4];
    float ofy = dl*f0[1] + dv*f0[3] + dt*f0[5];

    float gx = ((-1.f + (2.f/511.f)*(float)xo) + ofx + 1.f)*256.f - 0.5f;
    float gy = ((-1.f + (2.f/511.f)*(float)yo) + ofy + 1.f)*256.f - 0.5f;
    gx = fminf(fmaxf(gx, 0.f), 511.f);
    gy = fminf(fmaxf(gy, 0.f), 511.f);

    float x0f = floorf(gx), y0f = floorf(gy);
    float wx = gx - x0f, wy = gy - y0f;
    int x0i = (int)x0f, y0i = (int)y0f;
    int x1i = min(x0i + 1, WWI-1), y1i = min(y0i + 1, HH-1);

    float cw[4] = {(1.f-wx)*(1.f-wy), wx*(1.f-wy), (1.f-wx)*wy, wx*wy};
    int   cp[4] = {y0i*WWI + x0i, y0i*WWI + x1i, y1i*WWI + x0i, y1i*WWI + x1i};

    const float* nb = neighbors + (size_t)n*3*HWP;
    const float* Fn = flows + (size_t)(n+1)*6*HWP;

    float s0=0.f,s1=0.f,s2=0.f;
    float l0=0.f,l1=0.f,v0=0.f,v1=0.f,t0=0.f,t1=0.f;
    #pragma unroll
    for (int c = 0; c < 4; c++) {
      int p = cp[c];
      float ww = cw[c];
      float n0 = nb[p];
      float n1 = nb[HWP + p];
      float n2 = nb[2*HWP + p];
      if (fl) {
        n0 /= alb[p];
        n1 /= alb[HWP + p];
        n2 /= alb[2*HWP + p];
      }
      s0 += ww*n0; s1 += ww*n1; s2 += ww*n2;
      l0 += ww*Fn[p];             l1 += ww*Fn[HWP + p];
      v0 += ww*Fn[2*HWP + p];     v1 += ww*Fn[3*HWP + p];
      t0 += ww*Fn[4*HWP + p];     t1 += ww*Fn[5*HWP + p];
    }

    float wi0 = fl ? s0*albp[0] : s0;
    float wi1 = fl ? s1*albp[1] : s1;
    float wi2 = fl ? s2*albp[2] : s2;

    float obx = dl*l0 + dv*v0 + dt*t0;
    float oby = dl*l1 + dv*v1 + dt*t1;
    float dist = fabsf(ofx - obx) + fabsf(ofy - oby);
    float wgt = expf(-51.2f * dist);

    wsum += wgt;
    num0 += wgt*wi0; num1 += wgt*wi1; num2 += wgt*wi2;
  }

  float inv = 1.f / (wsum + 1e-5f);
  out[idx]         = num0*inv;
  out[HWP + idx]   = num1*inv;
  out[2*HWP + idx] = num2*inv;
}

// ---------------- launch ----------------
extern "C" void kernel_launch(void* const* d_in, const int* in_sizes, int n_in,
                              void* d_out, int out_size, void* d_ws, size_t ws_size,
                              hipStream_t stream) {
  const float* x         = (const float*)d_in[0];
  const float* neighbors = (const float*)d_in[1];
  const int*   aidx      = (const int*)d_in[2];
  const float* wts[10];
  const float* bis[10];
  for (int i = 0; i < 9; i++) { wts[i] = (const float*)d_in[3+2*i]; bis[i] = (const float*)d_in[4+2*i]; }
  wts[9] = (const float*)d_in[21];   // wf
  bis[9] = (const float*)d_in[22];   // bf
  const float* albedos = (const float*)d_in[23];

  float* wk   = (float*)d_ws;
  float* bufS = wk;                   // 792 floats (layer0 out)
  float* bufA = wk + 800;             // up to 4,718,592 floats
  float* bufB = bufA + 4718592;       // up to 12,582,912 floats
  size_t need = (size_t)(800 + 4718592 + 12582912) * 4;
  if (ws_size < need) return;

  // Folded weights in bufA slack [3,200,000, 3,415,040): above L7's peak bufA
  // use (3,145,728 floats); overwritten only by k_final2 (4,718,592) AFTER L8
  // consumed them. No workspace growth.
  float* wf1 = bufA + 3200000;            // 64*66*16 = 67584
  float* wf2 = wf1 + 67584;               // 64*64*16 = 65536
  float* wf3 = wf2 + 65536;               // 32*64*16 = 32768
  float* wf4 = wf3 + 32768;               // 32*32*16 = 16384
  float* wf5 = wf4 + 16384;               // 32*32*16 = 16384
  float* wf6 = wf5 + 16384;               // 16*32*16 = 8192
  float* wf7 = wf6 + 8192;                // 16*16*16 = 4096
  float* wf8 = wf7 + 4096;                // 16*16*16 = 4096

  // prep: fold (blocks 0-52) + layer0 (block 53) -- one dispatch.
  k_prep<<<54, 256, 0, stream>>>(x, wts[0], bis[0], bufS,
                                 wts[1], wts[2], wts[3], wts[4], wts[5], wts[6], wts[7], wts[8],
                                 wf1, wf2, wf3, wf4, wf5, wf6, wf7, wf8);

  auto blocks = [](int total){ return (total + 255) / 256; };

  // L1-L5: scalar parity upconv, grid (npix/256, CO). LDS = 4*(CIN+1)*16 B.
  {
    dim3 g1(blocks(3*4*4), 64), g2(blocks(3*8*8), 64);
    dim3 g3(blocks(3*16*16), 32), g4(blocks(3*32*32), 32), g5(blocks(3*64*64), 32);
    k_upconv_s<66><<<g1, 256, (size_t)4*(66+1)*16, stream>>>(bufS, bufA, wf1, bis[1], 3, 64, 2);
    k_upconv_s<64><<<g2, 256, (size_t)4*(64+1)*16, stream>>>(bufA, bufB, wf2, bis[2], 3, 64, 4);
    k_upconv_s<64><<<g3, 256, (size_t)4*(64+1)*16, stream>>>(bufB, bufA, wf3, bis[3], 3, 32, 8);
    k_upconv_s<32><<<g4, 256, (size_t)4*(32+1)*16, stream>>>(bufA, bufB, wf4, bis[4], 3, 32, 16);
    k_upconv_s<32><<<g5, 256, (size_t)4*(32+1)*16, stream>>>(bufB, bufA, wf5, bis[5], 3, 32, 32);
  }

  // L6-L8: P=4 positions x COB=4 channels per thread (ds_read/output = Cin/4).
  {
    dim3 g6(blocks(3*128*32), 4);    // 48 x 4
    dim3 g7(blocks(3*256*64), 4);    // 192 x 4
    dim3 g8(blocks(3*512*128), 4);   // 768 x 4
    k_upconv_wP<4,4><<<g6, 256, (size_t)4*(32*4+1)*16, stream>>>(bufA, bufB, wf6, bis[6], 3, 32, 16, 64);
    k_upconv_wP<4,4><<<g7, 256, (size_t)4*(16*4+1)*16, stream>>>(bufB, bufA, wf7, bis[7], 3, 16, 16, 128);
    k_upconv_wP<4,4><<<g8, 256, (size_t)4*(16*4+1)*16, stream>>>(bufA, bufB, wf8, bis[8], 3, 16, 16, 256);
  }

  // final: paired-x conv + tanh (+XCD swizzle).
  k_final2<<<blocks(3*HH*(WWI/2)), 256, 0, stream>>>(bufB, bufA, wts[9], bis[9]);
  k_blend<<<blocks(HWP), 256, 0, stream>>>(x, neighbors, aidx, albedos, bufA, (float*)d_out);
}